// Round 3
// baseline (26.781 us; speedup 1.0000x reference)
//
#include <hip/hip_runtime.h>
#include <hip/hip_bf16.h>

// RGCN fused: out = relu( [x | agg_r0..agg_r15] @ [w_self | w_rel]^T )
// B=4096, S=10, R=16, F=128, K_total=2176.
// v3: BT=8 -> 512 blocks (2 resident/CU for cross-block phase overlap),
// 512 thr @ <=128 VGPR (4 waves/SIMD). K-split phase B + LDS reduction.
// W pre-packed bf16 fragments in d_ws (wprep).

#define BT      8
#define LDA     2184           // bf16 elems per A_t row (2176 + 8 pad)
#define NTHR    512
#define K_STEPS 68             // 2176 / 32
#define W2_UNITS (K_STEPS * 8) // 544 (ks, otile) units
#define W2_BYTES (W2_UNITS * 64 * 16)  // 557,056

typedef __attribute__((ext_vector_type(8))) short short8;  // 8 bf16
typedef __attribute__((ext_vector_type(4))) float f32x4;   // MFMA acc

__device__ __forceinline__ unsigned int pk2_rne(float lo, float hi) {
  unsigned int r;
  asm("v_cvt_pk_bf16_f32 %0, %1, %2" : "=v"(r) : "v"(lo), "v"(hi));
  return r;
}

// ---- prep: W (fp32) -> bf16 fragments, layout [ks][ot][lane], 16B/lane ----
__global__ __launch_bounds__(256)
void wprep(const float* __restrict__ w_self, const float* __restrict__ w_rel,
           uint4* __restrict__ w2)
{
  const int u  = blockIdx.x * 4 + (threadIdx.x >> 6);   // 0..543
  const int l  = threadIdx.x & 63;
  const int ln = l & 15, lj = l >> 4;
  const int ks = u >> 3, ot = u & 7;
  const int o  = ot * 16 + ln;
  const int k0 = ks * 32 + lj * 8;
  const float* src;
  if (k0 < 128) src = w_self + o * 128 + k0;
  else {
    const int r = (k0 - 128) >> 7, kc = (k0 - 128) & 127;
    src = w_rel + ((size_t)(r * 128 + o)) * 128 + kc;
  }
  const float4 a = *(const float4*)src;
  const float4 b = *(const float4*)(src + 4);
  uint4 v;
  v.x = pk2_rne(a.x, a.y); v.y = pk2_rne(a.z, a.w);
  v.z = pk2_rne(b.x, b.y); v.w = pk2_rne(b.z, b.w);
  w2[u * 64 + l] = v;
}

__global__ __launch_bounds__(NTHR, 4)
void rgcn_fused(const float* __restrict__ emb,
                const int*   __restrict__ nodes,
                const int*   __restrict__ neighbors,
                const int*   __restrict__ rel_mask,
                const uint4* __restrict__ w2,
                float*       __restrict__ out)
{
  __shared__ alignas(16) char smem[40064];
  unsigned short* A_t = (unsigned short*)smem;                  // [8][2184] bf16
  float (*mscale)[10][16] = (float (*)[10][16])(smem + 34944);  // [8][10][16]

  const int t  = threadIdx.x;
  const int b0 = blockIdx.x * BT;
  const int l  = t & 63;
  const int w  = t >> 6;

  // ---------- A0 + A issue: mask loads first, then gathers ----------
  // mscale[b][s][r] = m/(count+eps)
  int mb[10];
  const int bi0 = t >> 4, r0 = t & 15;                 // t<128: (node,relation)
  if (t < 128) {
    const int* mp = rel_mask + (size_t)(b0 + bi0) * 160 + r0;
    #pragma unroll
    for (int s = 0; s < 10; ++s) mb[s] = mp[s * 16];
  }

  // gathers: wave w owns node slot w; lane covers 2 features (float2)
  const int bi = w;                                    // node slot 0..7
  const int f0 = l * 2;
  const int b  = b0 + bi;
  const int node = nodes[b];
  int nb[10];
  #pragma unroll
  for (int s = 0; s < 10; ++s) nb[s] = neighbors[b * 10 + s];
  float2 ne[10];
  #pragma unroll
  for (int s = 0; s < 10; ++s)
    ne[s] = *(const float2*)(emb + (size_t)nb[s] * 128 + f0);
  const float2 x2 = *(const float2*)(emb + (size_t)node * 128 + f0);

  if (t < 128) {
    int c = 0;
    #pragma unroll
    for (int s = 0; s < 10; ++s) c += mb[s];
    const float inv = 1.0f / ((float)c + 1e-10f);
    #pragma unroll
    for (int s = 0; s < 10; ++s) mscale[bi0][s][r0] = mb[s] ? inv : 0.0f;
  }
  __syncthreads();

  // ---------- A: masked means -> A_t (bf16) ----------
  {
    char* arow = (char*)A_t + bi * (LDA * 2);
    *(unsigned int*)(arow + f0 * 2) = pk2_rne(x2.x, x2.y);   // self, k in [0,128)

    float acc[16][2];
    #pragma unroll
    for (int r = 0; r < 16; ++r) { acc[r][0] = 0.f; acc[r][1] = 0.f; }
    #pragma unroll
    for (int s = 0; s < 10; ++s) {
      const float4 m0 = *(const float4*)(&mscale[bi][s][0]);
      const float4 m1 = *(const float4*)(&mscale[bi][s][4]);
      const float4 m2 = *(const float4*)(&mscale[bi][s][8]);
      const float4 m3 = *(const float4*)(&mscale[bi][s][12]);
      const float m[16] = {m0.x,m0.y,m0.z,m0.w, m1.x,m1.y,m1.z,m1.w,
                           m2.x,m2.y,m2.z,m2.w, m3.x,m3.y,m3.z,m3.w};
      const float2 v = ne[s];
      #pragma unroll
      for (int r = 0; r < 16; ++r) {
        acc[r][0] += m[r] * v.x;
        acc[r][1] += m[r] * v.y;
      }
    }
    #pragma unroll
    for (int r = 0; r < 16; ++r)                       // agg_r, k in [128+128r, ...)
      *(unsigned int*)(arow + 256 + r * 256 + f0 * 2) = pk2_rne(acc[r][0], acc[r][1]);
  }
  __syncthreads();

  // ---------- B: K-split GEMM; wave w owns its k-step range, all 128 cols ----------
  const int ln = l & 15, lj = l >> 4;
  f32x4 acc[8];
  #pragma unroll
  for (int ot = 0; ot < 8; ++ot) acc[ot] = (f32x4){0.f, 0.f, 0.f, 0.f};
  {
    const int ksb = (w < 4) ? w * 9 : 36 + (w - 4) * 8;
    const int kse = ksb + ((w < 4) ? 9 : 8);
    // rows 8..15 of the 16x16 tile: duplicate rows 0..7 (discarded at store)
    const char* arow = (const char*)A_t + (ln & 7) * (LDA * 2);
    for (int ks = ksb; ks < kse; ++ks) {
      const short8 a = *(const short8*)(arow + ks * 64 + lj * 16);
      #pragma unroll
      for (int ot = 0; ot < 8; ++ot) {
        union { uint4 u; short8 s; } wv;
        wv.u = w2[(ks * 8 + ot) * 64 + l];
        acc[ot] = __builtin_amdgcn_mfma_f32_16x16x32_bf16(a, wv.s, acc[ot], 0, 0, 0);
      }
    }
  }
  __syncthreads();

  // ---------- C: per-k-group partials to LDS (aliases A_t) ----------
  {
    float* P = (float*)smem;                           // [8][8][132] f32
    if (lj < 2) {                                      // rows 0..7 are real
      #pragma unroll
      for (int ot = 0; ot < 8; ++ot) {
        const int o = ot * 16 + ln;
        #pragma unroll
        for (int j = 0; j < 4; ++j)
          P[(w * 8 + lj * 4 + j) * 132 + o] = acc[ot][j];
      }
    }
  }
  __syncthreads();

  // ---------- D: 8-way reduce + relu + store ----------
  {
    const float* P = (const float*)smem;
    const int row = w;                                 // wave per row
    const int o0 = l * 2;
    float s0 = 0.f, s1 = 0.f;
    #pragma unroll
    for (int g = 0; g < 8; ++g) {
      const float2 p = *(const float2*)(P + (g * 8 + row) * 132 + o0);
      s0 += p.x; s1 += p.y;
    }
    float2 o2; o2.x = fmaxf(s0, 0.f); o2.y = fmaxf(s1, 0.f);
    *(float2*)(out + (size_t)(b0 + row) * 128 + o0) = o2;
  }
}

extern "C" void kernel_launch(void* const* d_in, const int* in_sizes, int n_in,
                              void* d_out, int out_size, void* d_ws, size_t ws_size,
                              hipStream_t stream) {
  const float* emb       = (const float*)d_in[0];
  const float* w_self    = (const float*)d_in[1];
  const float* w_rel     = (const float*)d_in[2];
  const int*   nodes     = (const int*)d_in[3];
  const int*   neighbors = (const int*)d_in[4];
  const int*   rel_mask  = (const int*)d_in[5];
  float* out = (float*)d_out;
  (void)in_sizes; (void)n_in; (void)out_size; (void)ws_size;

  wprep<<<136, 256, 0, stream>>>(w_self, w_rel, (uint4*)d_ws);
  rgcn_fused<<<4096 / BT, NTHR, 0, stream>>>(
      emb, nodes, neighbors, rel_mask, (const uint4*)d_ws, out);
}